// Round 1
// baseline (1924.585 us; speedup 1.0000x reference)
//
#include <hip/hip_runtime.h>
#include <math.h>

typedef __attribute__((ext_vector_type(8))) short bf16x8;
typedef __attribute__((ext_vector_type(4))) float f32x4;

#define MFMA16(a, b, c) __builtin_amdgcn_mfma_f32_16x16x32_bf16(a, b, c, 0, 0, 0)

__device__ __forceinline__ short f2bf(float f) {
    union { float f; unsigned int u; } v; v.f = f;
    unsigned int u = v.u;
    u += 0x7FFFu + ((u >> 16) & 1u);   // round-to-nearest-even
    return (short)(u >> 16);
}

// ---------------------------------------------------------------- convert
__global__ __launch_bounds__(256) void cvt_kernel(const float* __restrict__ src,
                                                  short* __restrict__ dst, int n4) {
    int i = blockIdx.x * 256 + threadIdx.x;
    if (i >= n4) return;
    float4 v = ((const float4*)src)[i];
    short4 o;
    o.x = f2bf(v.x); o.y = f2bf(v.y); o.z = f2bf(v.z); o.w = f2bf(v.w);
    ((short4*)dst)[i] = o;
}

// ------------------------------------------------- transpose fp32[R][C] -> bf16[C][R]
__global__ __launch_bounds__(256) void transpose_cvt_kernel(const float* __restrict__ src,
                                                            short* __restrict__ dst,
                                                            int R, int C) {
    __shared__ short tile[32][33];
    const int t = threadIdx.x;
    const int r0 = blockIdx.y << 5, c0 = blockIdx.x << 5;
    {
        int tr = t >> 3, tc = (t & 7) << 2;
        float4 v = *(const float4*)(src + (size_t)(r0 + tr) * C + c0 + tc);
        tile[tr][tc + 0] = f2bf(v.x);
        tile[tr][tc + 1] = f2bf(v.y);
        tile[tr][tc + 2] = f2bf(v.z);
        tile[tr][tc + 3] = f2bf(v.w);
    }
    __syncthreads();
    {
        int on = t >> 3, ok = (t & 7) << 2;
        short4 o;
        o.x = tile[ok + 0][on]; o.y = tile[ok + 1][on];
        o.z = tile[ok + 2][on]; o.w = tile[ok + 3][on];
        *(short4*)(dst + (size_t)(c0 + on) * R + r0 + ok) = o;
    }
}

// ---------------------------------------------------------------- GEMM
// C[M][N] = A[M][K] * Bt[N][K]^T   (both bf16, fp32 accum)
// MODE 0: QKV epilogue (+bias, scale Q, scatter to Q[bh][s][d], K[bh][s][d], V[bh][d][s])
// MODE 1: out epilogue (+bias, fp32 store)
template <int MODE>
__global__ __launch_bounds__(256) void gemm_kernel(const short* __restrict__ A,
                                                   const short* __restrict__ Bt,
                                                   const float* __restrict__ bias,
                                                   short* __restrict__ Qo,
                                                   short* __restrict__ Ko,
                                                   short* __restrict__ Vo,
                                                   float* __restrict__ Co,
                                                   int M, int N, int K) {
    __shared__ short As[128][40];   // [m][k], pad 32->40 (row 80B, 16B aligned)
    __shared__ short Bs[128][40];   // [n][k]
    const int t = threadIdx.x;
    const int m0 = blockIdx.y << 7;
    const int n0 = blockIdx.x << 7;
    const int lane = t & 63;
    const int w = t >> 6;
    const int l16 = lane & 15;
    const int quad = lane >> 4;
    const int wm = (w >> 1) << 6;   // 0 / 64
    const int wn = (w & 1) << 6;

    const int sr = t >> 2;          // staging row 0..63
    const int sc = (t & 3) << 3;    // staging col 0,8,16,24

    f32x4 acc[4][4];
#pragma unroll
    for (int i = 0; i < 4; ++i)
#pragma unroll
        for (int j = 0; j < 4; ++j) acc[i][j] = (f32x4){0.f, 0.f, 0.f, 0.f};

    for (int k0 = 0; k0 < K; k0 += 32) {
#pragma unroll
        for (int rr = 0; rr < 2; ++rr) {
            int row = sr + (rr << 6);
            *(bf16x8*)&As[row][sc] = *(const bf16x8*)(A + (size_t)(m0 + row) * K + k0 + sc);
            *(bf16x8*)&Bs[row][sc] = *(const bf16x8*)(Bt + (size_t)(n0 + row) * K + k0 + sc);
        }
        __syncthreads();
        bf16x8 af[4], bfr[4];
#pragma unroll
        for (int mb = 0; mb < 4; ++mb)
            af[mb] = *(const bf16x8*)&As[wm + (mb << 4) + l16][quad << 3];
#pragma unroll
        for (int nb = 0; nb < 4; ++nb)
            bfr[nb] = *(const bf16x8*)&Bs[wn + (nb << 4) + l16][quad << 3];
#pragma unroll
        for (int mb = 0; mb < 4; ++mb)
#pragma unroll
            for (int nb = 0; nb < 4; ++nb)
                acc[mb][nb] = MFMA16(af[mb], bfr[nb], acc[mb][nb]);
        __syncthreads();
    }

    const float qscale = 0.08838834764831845f;  // 1/sqrt(128)
#pragma unroll
    for (int nb = 0; nb < 4; ++nb) {
        int gn = n0 + wn + (nb << 4) + l16;
        float bv = bias[gn];
        int head = 0, f = 0;
        if (MODE == 0) { head = gn / 384; f = gn - head * 384; }
#pragma unroll
        for (int mb = 0; mb < 4; ++mb) {
#pragma unroll
            for (int r = 0; r < 4; ++r) {
                int gm = m0 + wm + (mb << 4) + (quad << 2) + r;
                float v = acc[mb][nb][r] + bv;
                if (MODE == 0) {
                    int b = gm >> 11, s = gm & 2047;
                    int bhh = (b << 5) + head;
                    if (f < 128) {
                        Qo[((size_t)bhh * 2048 + s) * 128 + f] = f2bf(v * qscale);
                    } else if (f < 256) {
                        Ko[((size_t)bhh * 2048 + s) * 128 + (f - 128)] = f2bf(v);
                    } else {
                        Vo[((size_t)bhh * 128 + (f - 256)) * 2048 + s] = f2bf(v);
                    }
                } else {
                    Co[(size_t)gm * N + gn] = v;
                }
            }
        }
    }
}

// ---------------------------------------------------------------- flash attention
// grid (S/64, B*NH), 256 threads. Q[bh][s][d], K[bh][s][d], V[bh][d][s] (bf16).
// Out: attn[b*S+q][h*128+d] bf16.
__global__ __launch_bounds__(256) void attn_kernel(const short* __restrict__ Q,
                                                   const short* __restrict__ Kt,
                                                   const short* __restrict__ Vt,
                                                   const float* __restrict__ alibi,
                                                   const int* __restrict__ amask,
                                                   short* __restrict__ Ot) {
    __shared__ short Ks[32][136];    // [key][d], pad 128->136
    __shared__ short Vs[128][40];    // [d][key], pad 32->40
    __shared__ short Ps[4][16][40];  // per wave [q][key]
    const int t = threadIdx.x;
    const int w = t >> 6;
    const int lane = t & 63;
    const int l16 = lane & 15;
    const int quad = lane >> 4;
    const int qt = blockIdx.x;
    const int bh = blockIdx.y;
    const int b = bh >> 5;
    const int h = bh & 31;
    const int q0t = qt << 6;

    const short* Qp = Q + (size_t)bh * 2048 * 128;
    const short* Kp = Kt + (size_t)bh * 2048 * 128;
    const short* Vp = Vt + (size_t)bh * 128 * 2048;
    const float* alp = alibi + (size_t)bh * 2048;
    const int* amp = amask + (size_t)b * 2048;

    // Q fragments pinned in registers for the whole KV loop
    bf16x8 aq[4];
    const int myq = q0t + (w << 4) + l16;
#pragma unroll
    for (int kd = 0; kd < 4; ++kd)
        aq[kd] = *(const bf16x8*)(Qp + (size_t)myq * 128 + (kd << 5) + (quad << 3));

    f32x4 acc[8];
#pragma unroll
    for (int c = 0; c < 8; ++c) acc[c] = (f32x4){0.f, 0.f, 0.f, 0.f};
    float mrow[4], lrow[4];
#pragma unroll
    for (int r = 0; r < 4; ++r) { mrow[r] = -__builtin_inff(); lrow[r] = 0.f; }

    const int ktiles = (q0t >> 5) + 2;
    for (int kt = 0; kt < ktiles; ++kt) {
        const int kk = kt << 5;
        __syncthreads();  // protect Ks/Vs from overwrite
        {   // stage K tile [32][128]
            int r = t >> 4, c = (t & 15) << 3;
            *(bf16x8*)&Ks[r][c] = *(const bf16x8*)(Kp + (size_t)(kk + r) * 128 + c);
            *(bf16x8*)&Ks[r + 16][c] = *(const bf16x8*)(Kp + (size_t)(kk + r + 16) * 128 + c);
            // stage V tile transposed-source: Vs[d][key]
            int d = t >> 1, kc = (t & 1) << 4;
            *(bf16x8*)&Vs[d][kc] = *(const bf16x8*)(Vp + (size_t)d * 2048 + kk + kc);
            *(bf16x8*)&Vs[d][kc + 8] = *(const bf16x8*)(Vp + (size_t)d * 2048 + kk + kc + 8);
        }
        __syncthreads();
        // QK^T: 16 q-rows x 32 keys
        f32x4 sf[2];
        sf[0] = (f32x4){0.f, 0.f, 0.f, 0.f};
        sf[1] = (f32x4){0.f, 0.f, 0.f, 0.f};
#pragma unroll
        for (int nb = 0; nb < 2; ++nb)
#pragma unroll
            for (int kd = 0; kd < 4; ++kd) {
                bf16x8 bk = *(const bf16x8*)&Ks[(nb << 4) + l16][(kd << 5) + (quad << 3)];
                sf[nb] = MFMA16(aq[kd], bk, sf[nb]);
            }
        // online softmax (C layout: row = quad*4+r, col = l16)
        const int qrb = q0t + (w << 4) + (quad << 2);
        float alpha[4];
#pragma unroll
        for (int r = 0; r < 4; ++r) {
            int qr = qrb + r;
            int key0 = kk + l16, key1 = key0 + 16;
            float s0 = (key0 <= qr && amp[key0] > 0) ? sf[0][r] + alp[key0] : -3.0e38f;
            float s1 = (key1 <= qr && amp[key1] > 0) ? sf[1][r] + alp[key1] : -3.0e38f;
            float mx = fmaxf(s0, s1);
            mx = fmaxf(mx, __shfl_xor(mx, 1));
            mx = fmaxf(mx, __shfl_xor(mx, 2));
            mx = fmaxf(mx, __shfl_xor(mx, 4));
            mx = fmaxf(mx, __shfl_xor(mx, 8));
            float mnew = fmaxf(mrow[r], mx);
            float a = __expf(mrow[r] - mnew);
            float p0 = __expf(s0 - mnew);
            float p1 = __expf(s1 - mnew);
            mrow[r] = mnew;
            alpha[r] = a;
            float ps = p0 + p1;
            ps += __shfl_xor(ps, 1);
            ps += __shfl_xor(ps, 2);
            ps += __shfl_xor(ps, 4);
            ps += __shfl_xor(ps, 8);
            lrow[r] = lrow[r] * a + ps;
            Ps[w][(quad << 2) + r][l16] = f2bf(p0);
            Ps[w][(quad << 2) + r][l16 + 16] = f2bf(p1);
        }
        __syncthreads();  // make P stores visible (also a compiler fence)
        // PV: acc = alpha*acc + P @ V
        bf16x8 ap = *(const bf16x8*)&Ps[w][l16][quad << 3];
#pragma unroll
        for (int c = 0; c < 8; ++c) {
            bf16x8 bv = *(const bf16x8*)&Vs[(c << 4) + l16][quad << 3];
            f32x4 ac = acc[c];
            ac[0] *= alpha[0]; ac[1] *= alpha[1]; ac[2] *= alpha[2]; ac[3] *= alpha[3];
            acc[c] = MFMA16(ap, bv, ac);
        }
    }
    // epilogue: divide by l, write attn[b*S+q][h*128+d]
    float inv[4];
#pragma unroll
    for (int r = 0; r < 4; ++r) inv[r] = (lrow[r] > 0.f) ? 1.0f / lrow[r] : 0.f;
    const int qbase = q0t + (w << 4) + (quad << 2);
#pragma unroll
    for (int c = 0; c < 8; ++c) {
        int d = (c << 4) + l16;
#pragma unroll
        for (int r = 0; r < 4; ++r) {
            int q = qbase + r;
            Ot[(size_t)(b * 2048 + q) * 4096 + h * 128 + d] = f2bf(acc[c][r] * inv[r]);
        }
    }
}

// ---------------------------------------------------------------- launch
extern "C" void kernel_launch(void* const* d_in, const int* in_sizes, int n_in,
                              void* d_out, int out_size, void* d_ws, size_t ws_size,
                              hipStream_t stream) {
    const float* hidden = (const float*)d_in[0];
    const float* alibi  = (const float*)d_in[1];
    const float* w_qkv  = (const float*)d_in[2];
    const float* b_qkv  = (const float*)d_in[3];
    const float* w_out  = (const float*)d_in[4];
    const float* b_out  = (const float*)d_in[5];
    const int*   amask  = (const int*)d_in[6];
    float* out = (float*)d_out;

    char* ws = (char*)d_ws;
    // layout (bytes):
    //   [0, 33.5M)      hid_bf16  (later aliased as attn_out bf16)
    //   [33.5M,134.2M)  wqkv_t bf16 [12288][4096]  (later aliased as wout_t)
    //   [134.2M,167.8M) Q bf16 [64][2048][128]
    //   [167.8M,201.3M) K bf16 [64][2048][128]
    //   [201.3M,224M+)  V bf16 [64][128][2048]
    short* hid_bf = (short*)(ws);
    short* wqkv_t = (short*)(ws + 33554432ull);
    short* wout_t = wqkv_t;  // reused after QKV GEMM consumes wqkv_t
    short* Qb     = (short*)(ws + 134217728ull);
    short* Kb     = (short*)(ws + 167772160ull);
    short* Vb     = (short*)(ws + 201326592ull);
    short* attn_o = hid_bf;  // reused after QKV GEMM consumes hid_bf

    cvt_kernel<<<16384, 256, 0, stream>>>(hidden, hid_bf, 4194304);
    transpose_cvt_kernel<<<dim3(384, 128), 256, 0, stream>>>(w_qkv, wqkv_t, 4096, 12288);
    gemm_kernel<0><<<dim3(96, 32), 256, 0, stream>>>(hid_bf, wqkv_t, b_qkv,
                                                     Qb, Kb, Vb, nullptr,
                                                     4096, 12288, 4096);
    transpose_cvt_kernel<<<dim3(128, 128), 256, 0, stream>>>(w_out, wout_t, 4096, 4096);
    attn_kernel<<<dim3(32, 64), 256, 0, stream>>>(Qb, Kb, Vb, alibi, amask, attn_o);
    gemm_kernel<1><<<dim3(32, 32), 256, 0, stream>>>(attn_o, wout_t, b_out,
                                                     nullptr, nullptr, nullptr, out,
                                                     4096, 4096, 4096);
}

// Round 2
// 1617.612 us; speedup vs baseline: 1.1898x; 1.1898x over previous
//
#include <hip/hip_runtime.h>
#include <math.h>

typedef __attribute__((ext_vector_type(8))) short bf16x8;
typedef __attribute__((ext_vector_type(4))) float f32x4;

#define MFMA16(a, b, c) __builtin_amdgcn_mfma_f32_16x16x32_bf16(a, b, c, 0, 0, 0)

// global->LDS async copy, 16B per lane. LDS dest = wave-uniform base + lane*16.
#define GLD_LDS16(g, l)                                                          \
    __builtin_amdgcn_global_load_lds(                                            \
        (const __attribute__((address_space(1))) unsigned int*)(g),              \
        (__attribute__((address_space(3))) unsigned int*)(l), 16, 0, 0)

__device__ __forceinline__ short f2bf(float f) {
    union { float f; unsigned int u; } v; v.f = f;
    unsigned int u = v.u;
    u += 0x7FFFu + ((u >> 16) & 1u);   // round-to-nearest-even
    return (short)(u >> 16);
}

// ---------------------------------------------------------------- convert
__global__ __launch_bounds__(256) void cvt_kernel(const float* __restrict__ src,
                                                  short* __restrict__ dst, int n4) {
    int i = blockIdx.x * 256 + threadIdx.x;
    if (i >= n4) return;
    float4 v = ((const float4*)src)[i];
    short4 o;
    o.x = f2bf(v.x); o.y = f2bf(v.y); o.z = f2bf(v.z); o.w = f2bf(v.w);
    ((short4*)dst)[i] = o;
}

// ------------------------------------------------- transpose fp32[R][C] -> bf16[C][R]
__global__ __launch_bounds__(256) void transpose_cvt_kernel(const float* __restrict__ src,
                                                            short* __restrict__ dst,
                                                            int R, int C) {
    __shared__ short tile[32][33];
    const int t = threadIdx.x;
    const int r0 = blockIdx.y << 5, c0 = blockIdx.x << 5;
    {
        int tr = t >> 3, tc = (t & 7) << 2;
        float4 v = *(const float4*)(src + (size_t)(r0 + tr) * C + c0 + tc);
        tile[tr][tc + 0] = f2bf(v.x);
        tile[tr][tc + 1] = f2bf(v.y);
        tile[tr][tc + 2] = f2bf(v.z);
        tile[tr][tc + 3] = f2bf(v.w);
    }
    __syncthreads();
    {
        int on = t >> 3, ok = (t & 7) << 2;
        short4 o;
        o.x = tile[ok + 0][on]; o.y = tile[ok + 1][on];
        o.z = tile[ok + 2][on]; o.w = tile[ok + 3][on];
        *(short4*)(dst + (size_t)(c0 + on) * R + r0 + ok) = o;
    }
}

// ---------------------------------------------------------------- GEMM (m97 structure)
// C[M][N] = A[M][K] * Bt[N][K]^T   (bf16 in, fp32 accum)
// Unpadded LDS tiles + global_load_lds width-16 staging.
// MODE 0: QKV epilogue (+bias, scale Q, scatter Q[bh][s][d], K[bh][s][d], V[bh][d][s])
// MODE 1: out epilogue (+bias, fp32 store)
template <int MODE>
__global__ __launch_bounds__(256) void gemm_kernel(const short* __restrict__ A,
                                                   const short* __restrict__ Bt,
                                                   const float* __restrict__ bias,
                                                   short* __restrict__ Qo,
                                                   short* __restrict__ Ko,
                                                   short* __restrict__ Vo,
                                                   float* __restrict__ Co,
                                                   int M, int N, int K) {
    __shared__ short As[128][32];   // unpadded: required by global_load_lds layout
    __shared__ short Bs[128][32];
    const int t = threadIdx.x;
    const int m0 = blockIdx.y << 7;
    const int n0 = blockIdx.x << 7;
    const int lane = t & 63;
    const int w = t >> 6;
    const int l16 = lane & 15;
    const int quad = lane >> 4;
    const int wm = (w >> 1) << 6;
    const int wn = (w & 1) << 6;

    // staging: wave w covers chunks 2w, 2w+1; chunk = 16 rows (16*64B = 1024B = 64 lanes x 16B)
    const int c0c = w << 1;
    const int srow0 = (c0c << 4) + (lane >> 2);       // chunk c0c
    const int srow1 = srow0 + 16;                      // chunk c0c+1
    const int scol = (lane & 3) << 3;                  // shorts

    f32x4 acc[4][4];
#pragma unroll
    for (int i = 0; i < 4; ++i)
#pragma unroll
        for (int j = 0; j < 4; ++j) acc[i][j] = (f32x4){0.f, 0.f, 0.f, 0.f};

    for (int k0 = 0; k0 < K; k0 += 32) {
        __syncthreads();   // previous iteration's readers done
        GLD_LDS16(A + (size_t)(m0 + srow0) * K + k0 + scol, &As[srow0 & ~15][0]);
        GLD_LDS16(A + (size_t)(m0 + srow1) * K + k0 + scol, &As[srow1 & ~15][0]);
        GLD_LDS16(Bt + (size_t)(n0 + srow0) * K + k0 + scol, &Bs[srow0 & ~15][0]);
        GLD_LDS16(Bt + (size_t)(n0 + srow1) * K + k0 + scol, &Bs[srow1 & ~15][0]);
        __syncthreads();   // vmcnt(0) drained before barrier => LDS ready
        bf16x8 af[4], bfr[4];
#pragma unroll
        for (int mb = 0; mb < 4; ++mb)
            af[mb] = *(const bf16x8*)&As[wm + (mb << 4) + l16][quad << 3];
#pragma unroll
        for (int nb = 0; nb < 4; ++nb)
            bfr[nb] = *(const bf16x8*)&Bs[wn + (nb << 4) + l16][quad << 3];
#pragma unroll
        for (int mb = 0; mb < 4; ++mb)
#pragma unroll
            for (int nb = 0; nb < 4; ++nb)
                acc[mb][nb] = MFMA16(af[mb], bfr[nb], acc[mb][nb]);
    }

    const float qscale = 0.08838834764831845f;  // 1/sqrt(128)
#pragma unroll
    for (int nb = 0; nb < 4; ++nb) {
        int gn = n0 + wn + (nb << 4) + l16;
        float bv = bias[gn];
        int head = 0, f = 0;
        if (MODE == 0) { head = gn / 384; f = gn - head * 384; }
#pragma unroll
        for (int mb = 0; mb < 4; ++mb) {
#pragma unroll
            for (int r = 0; r < 4; ++r) {
                int gm = m0 + wm + (mb << 4) + (quad << 2) + r;
                float v = acc[mb][nb][r] + bv;
                if (MODE == 0) {
                    int b = gm >> 11, s = gm & 2047;
                    int bhh = (b << 5) + head;
                    if (f < 128) {
                        Qo[((size_t)bhh * 2048 + s) * 128 + f] = f2bf(v * qscale);
                    } else if (f < 256) {
                        Ko[((size_t)bhh * 2048 + s) * 128 + (f - 128)] = f2bf(v);
                    } else {
                        Vo[((size_t)bhh * 128 + (f - 256)) * 2048 + s] = f2bf(v);
                    }
                } else {
                    Co[(size_t)gm * N + gn] = v;
                }
            }
        }
    }
}

// ---------------------------------------------------------------- flash attention
// grid (32, 64): blockIdx.x -> qt = 31-bx (heavy tiles first), blockIdx.y = bh.
// 64 q-rows/block (16/wave), 64-key tiles, register prefetch of next K/V tile.
__global__ __launch_bounds__(256) void attn_kernel(const short* __restrict__ Q,
                                                   const short* __restrict__ Kt,
                                                   const short* __restrict__ Vt,
                                                   const float* __restrict__ alibi,
                                                   const int* __restrict__ amask,
                                                   short* __restrict__ Ot) {
    __shared__ short Ks[64][132];    // [key][d]  (pad 128->132: 66 dwords/row)
    __shared__ short Vs[128][68];    // [d][key]  (pad 64->68: 34 dwords/row)
    __shared__ short Ps[4][16][68];  // per-wave P tile [q][key]
    const int t = threadIdx.x;
    const int w = t >> 6;
    const int lane = t & 63;
    const int l16 = lane & 15;
    const int quad = lane >> 4;
    const int qt = 31 - blockIdx.x;          // heavy blocks dispatch first
    const int bh = blockIdx.y;
    const int b = bh >> 5;
    const int h = bh & 31;
    const int q0t = qt << 6;

    const short* Qp = Q + (size_t)bh * 2048 * 128;
    const short* Kp = Kt + (size_t)bh * 2048 * 128;
    const short* Vp = Vt + (size_t)bh * 128 * 2048;
    const float* alp = alibi + (size_t)bh * 2048;
    const int* amp = amask + (size_t)b * 2048;

    // staging coords (256 threads)
    const int kr = t >> 4, kc = (t & 15) << 3;   // K: 16 rows/round x 128 shorts
    const int vr = t >> 3, vc = (t & 7) << 3;    // V: 32 rows/round x 64 shorts

    // Q fragments pinned in registers
    bf16x8 aq[4];
    const int myq = q0t + (w << 4) + l16;
#pragma unroll
    for (int kd = 0; kd < 4; ++kd)
        aq[kd] = *(const bf16x8*)(Qp + (size_t)myq * 128 + (kd << 5) + (quad << 3));

    f32x4 acc[8];
#pragma unroll
    for (int c = 0; c < 8; ++c) acc[c] = (f32x4){0.f, 0.f, 0.f, 0.f};
    float mrow[4], lrow[4];
#pragma unroll
    for (int r = 0; r < 4; ++r) { mrow[r] = -__builtin_inff(); lrow[r] = 0.f; }

    const int ktiles = qt + 1;

    // prefetch tile 0 into registers
    bf16x8 Kreg[4], Vreg[4];
#pragma unroll
    for (int i = 0; i < 4; ++i) {
        Kreg[i] = *(const bf16x8*)(Kp + (size_t)(kr + (i << 4)) * 128 + kc);
        Vreg[i] = *(const bf16x8*)(Vp + (size_t)(vr + (i << 5)) * 2048 + vc);
    }

    for (int kt = 0; kt < ktiles; ++kt) {
        const int kk = kt << 6;
        __syncthreads();   // all waves done reading LDS from previous tile
#pragma unroll
        for (int i = 0; i < 4; ++i) {
            *(bf16x8*)&Ks[kr + (i << 4)][kc] = Kreg[i];
            *(bf16x8*)&Vs[vr + (i << 5)][vc] = Vreg[i];
        }
        if (kt + 1 < ktiles) {   // issue next tile's loads; they complete during compute
            const int nk = kk + 64;
#pragma unroll
            for (int i = 0; i < 4; ++i) {
                Kreg[i] = *(const bf16x8*)(Kp + (size_t)(nk + kr + (i << 4)) * 128 + kc);
                Vreg[i] = *(const bf16x8*)(Vp + (size_t)(vr + (i << 5)) * 2048 + nk + vc);
            }
        }
        __syncthreads();   // staged tile visible

        // per-lane alibi+mask bias for this tile's 4 key columns
        float biasv[4];
#pragma unroll
        for (int j = 0; j < 4; ++j) {
            int key = kk + (j << 4) + l16;
            biasv[j] = (amp[key] > 0) ? alp[key] : -3.0e38f;
        }

        // QK^T: 16 q-rows x 64 keys
        f32x4 sf[4];
#pragma unroll
        for (int nb = 0; nb < 4; ++nb) {
            sf[nb] = (f32x4){0.f, 0.f, 0.f, 0.f};
#pragma unroll
            for (int kd = 0; kd < 4; ++kd) {
                bf16x8 bk = *(const bf16x8*)&Ks[(nb << 4) + l16][(kd << 5) + (quad << 3)];
                sf[nb] = MFMA16(aq[kd], bk, sf[nb]);
            }
        }

        // online softmax (C layout: row = quad*4+r, col = l16)
        const int qrb = q0t + (w << 4) + (quad << 2);
        float alpha[4];
#pragma unroll
        for (int r = 0; r < 4; ++r) {
            int qr = qrb + r;
            float s[4];
#pragma unroll
            for (int j = 0; j < 4; ++j) {
                int key = kk + (j << 4) + l16;
                s[j] = (key <= qr) ? sf[j][r] + biasv[j] : -3.0e38f;
            }
            float mx = fmaxf(fmaxf(s[0], s[1]), fmaxf(s[2], s[3]));
            mx = fmaxf(mx, __shfl_xor(mx, 1));
            mx = fmaxf(mx, __shfl_xor(mx, 2));
            mx = fmaxf(mx, __shfl_xor(mx, 4));
            mx = fmaxf(mx, __shfl_xor(mx, 8));
            float mnew = fmaxf(mrow[r], mx);
            float a = __expf(mrow[r] - mnew);
            float p[4], ps = 0.f;
#pragma unroll
            for (int j = 0; j < 4; ++j) { p[j] = __expf(s[j] - mnew); ps += p[j]; }
            ps += __shfl_xor(ps, 1);
            ps += __shfl_xor(ps, 2);
            ps += __shfl_xor(ps, 4);
            ps += __shfl_xor(ps, 8);
            mrow[r] = mnew;
            alpha[r] = a;
            lrow[r] = lrow[r] * a + ps;
            int pq = (quad << 2) + r;
#pragma unroll
            for (int j = 0; j < 4; ++j)
                Ps[w][pq][(j << 4) + l16] = f2bf(p[j]);
        }

        // PV (same-wave LDS write->read; no barrier needed)
        bf16x8 ap0 = *(const bf16x8*)&Ps[w][l16][quad << 3];
        bf16x8 ap1 = *(const bf16x8*)&Ps[w][l16][32 + (quad << 3)];
#pragma unroll
        for (int c = 0; c < 8; ++c) {
            bf16x8 bv0 = *(const bf16x8*)&Vs[(c << 4) + l16][quad << 3];
            bf16x8 bv1 = *(const bf16x8*)&Vs[(c << 4) + l16][32 + (quad << 3)];
            f32x4 ac = acc[c];
            ac[0] *= alpha[0]; ac[1] *= alpha[1]; ac[2] *= alpha[2]; ac[3] *= alpha[3];
            ac = MFMA16(ap0, bv0, ac);
            acc[c] = MFMA16(ap1, bv1, ac);
        }
    }

    // epilogue: divide by l, write attn[b*S+q][h*128+d] (bf16)
    float inv[4];
#pragma unroll
    for (int r = 0; r < 4; ++r) inv[r] = (lrow[r] > 0.f) ? 1.0f / lrow[r] : 0.f;
    const int qbase = q0t + (w << 4) + (quad << 2);
#pragma unroll
    for (int c = 0; c < 8; ++c) {
        int d = (c << 4) + l16;
#pragma unroll
        for (int r = 0; r < 4; ++r) {
            int q = qbase + r;
            Ot[(size_t)(b * 2048 + q) * 4096 + h * 128 + d] = f2bf(acc[c][r] * inv[r]);
        }
    }
}

// ---------------------------------------------------------------- launch
extern "C" void kernel_launch(void* const* d_in, const int* in_sizes, int n_in,
                              void* d_out, int out_size, void* d_ws, size_t ws_size,
                              hipStream_t stream) {
    const float* hidden = (const float*)d_in[0];
    const float* alibi  = (const float*)d_in[1];
    const float* w_qkv  = (const float*)d_in[2];
    const float* b_qkv  = (const float*)d_in[3];
    const float* w_out  = (const float*)d_in[4];
    const float* b_out  = (const float*)d_in[5];
    const int*   amask  = (const int*)d_in[6];
    float* out = (float*)d_out;

    char* ws = (char*)d_ws;
    short* hid_bf = (short*)(ws);
    short* wqkv_t = (short*)(ws + 33554432ull);
    short* wout_t = wqkv_t;  // reused after QKV GEMM consumes wqkv_t
    short* Qb     = (short*)(ws + 134217728ull);
    short* Kb     = (short*)(ws + 167772160ull);
    short* Vb     = (short*)(ws + 201326592ull);
    short* attn_o = hid_bf;  // reused after QKV GEMM consumes hid_bf

    cvt_kernel<<<16384, 256, 0, stream>>>(hidden, hid_bf, 4194304);
    transpose_cvt_kernel<<<dim3(384, 128), 256, 0, stream>>>(w_qkv, wqkv_t, 4096, 12288);
    gemm_kernel<0><<<dim3(96, 32), 256, 0, stream>>>(hid_bf, wqkv_t, b_qkv,
                                                     Qb, Kb, Vb, nullptr,
                                                     4096, 12288, 4096);
    transpose_cvt_kernel<<<dim3(128, 128), 256, 0, stream>>>(w_out, wout_t, 4096, 4096);
    attn_kernel<<<dim3(32, 64), 256, 0, stream>>>(Qb, Kb, Vb, alibi, amask, attn_o);
    gemm_kernel<1><<<dim3(32, 32), 256, 0, stream>>>(attn_o, wout_t, b_out,
                                                     nullptr, nullptr, nullptr, out,
                                                     4096, 4096, 4096);
}

// Round 3
// 1383.533 us; speedup vs baseline: 1.3911x; 1.1692x over previous
//
#include <hip/hip_runtime.h>
#include <math.h>

typedef __attribute__((ext_vector_type(8))) short bf16x8;
typedef __attribute__((ext_vector_type(4))) float f32x4;

#define MFMA16(a, b, c) __builtin_amdgcn_mfma_f32_16x16x32_bf16(a, b, c, 0, 0, 0)

// global->LDS async copy, 16B per lane. LDS dest = wave-uniform base + lane*16.
#define GLD_LDS16(g, l)                                                          \
    __builtin_amdgcn_global_load_lds(                                            \
        (const __attribute__((address_space(1))) unsigned int*)(g),              \
        (__attribute__((address_space(3))) unsigned int*)(l), 16, 0, 0)

__device__ __forceinline__ short f2bf(float f) {
    union { float f; unsigned int u; } v; v.f = f;
    unsigned int u = v.u;
    u += 0x7FFFu + ((u >> 16) & 1u);   // round-to-nearest-even
    return (short)(u >> 16);
}

__device__ __forceinline__ short f2bf_trunc(float f) {
    union { float f; unsigned int u; } v; v.f = f;
    return (short)(v.u >> 16);
}

__device__ __forceinline__ float fexp2(float x) {
#if __has_builtin(__builtin_amdgcn_exp2f)
    return __builtin_amdgcn_exp2f(x);
#else
    return __expf(x * 0.6931471805599453f);
#endif
}

// ---------------------------------------------------------------- convert
__global__ __launch_bounds__(256) void cvt_kernel(const float* __restrict__ src,
                                                  short* __restrict__ dst, int n4) {
    int i = blockIdx.x * 256 + threadIdx.x;
    if (i >= n4) return;
    float4 v = ((const float4*)src)[i];
    short4 o;
    o.x = f2bf(v.x); o.y = f2bf(v.y); o.z = f2bf(v.z); o.w = f2bf(v.w);
    ((short4*)dst)[i] = o;
}

// ---------------------------------------------------- combined alibi/mask bias (x log2e)
__global__ __launch_bounds__(256) void bias_prep_kernel(const float* __restrict__ alibi,
                                                        const int* __restrict__ amask,
                                                        float* __restrict__ cb) {
    int i = blockIdx.x * 256 + threadIdx.x;   // i over 64*2048
    int bh = i >> 11, k = i & 2047;
    int b = bh >> 5;
    cb[i] = (amask[b * 2048 + k] > 0) ? alibi[i] * 1.4426950408889634f : -3.0e38f;
}

// ------------------------------------------------- transpose fp32[R][C] -> bf16[C][R]
__global__ __launch_bounds__(256) void transpose_cvt_kernel(const float* __restrict__ src,
                                                            short* __restrict__ dst,
                                                            int R, int C) {
    __shared__ short tile[32][33];
    const int t = threadIdx.x;
    const int r0 = blockIdx.y << 5, c0 = blockIdx.x << 5;
    {
        int tr = t >> 3, tc = (t & 7) << 2;
        float4 v = *(const float4*)(src + (size_t)(r0 + tr) * C + c0 + tc);
        tile[tr][tc + 0] = f2bf(v.x);
        tile[tr][tc + 1] = f2bf(v.y);
        tile[tr][tc + 2] = f2bf(v.z);
        tile[tr][tc + 3] = f2bf(v.w);
    }
    __syncthreads();
    {
        int on = t >> 3, ok = (t & 7) << 2;
        short4 o;
        o.x = tile[ok + 0][on]; o.y = tile[ok + 1][on];
        o.z = tile[ok + 2][on]; o.w = tile[ok + 3][on];
        *(short4*)(dst + (size_t)(c0 + on) * R + r0 + ok) = o;
    }
}

// ---------------------------------------------------------------- QKV GEMM
// m-fastest grid: blockIdx.x = m-tile (32), blockIdx.y = n-tile (96).
__global__ __launch_bounds__(256) void qkv_gemm_kernel(const short* __restrict__ A,
                                                       const short* __restrict__ Bt,
                                                       const float* __restrict__ bias,
                                                       short* __restrict__ Qo,
                                                       short* __restrict__ Ko,
                                                       short* __restrict__ Vo) {
    const int K = 4096;
    __shared__ short As[128][32];
    __shared__ short Bs[128][32];
    const int t = threadIdx.x;
    const int m0 = blockIdx.x << 7;
    const int n0 = blockIdx.y << 7;
    const int lane = t & 63;
    const int w = t >> 6;
    const int l16 = lane & 15;
    const int quad = lane >> 4;
    const int wm = (w >> 1) << 6;
    const int wn = (w & 1) << 6;

    const int srow0 = (w << 5) + (lane >> 2);
    const int srow1 = srow0 + 16;
    const int scol = (lane & 3) << 3;

    f32x4 acc[4][4];
#pragma unroll
    for (int i = 0; i < 4; ++i)
#pragma unroll
        for (int j = 0; j < 4; ++j) acc[i][j] = (f32x4){0.f, 0.f, 0.f, 0.f};

    for (int k0 = 0; k0 < K; k0 += 32) {
        __syncthreads();
        GLD_LDS16(A + (size_t)(m0 + srow0) * K + k0 + scol, &As[srow0 & ~15][0]);
        GLD_LDS16(A + (size_t)(m0 + srow1) * K + k0 + scol, &As[srow1 & ~15][0]);
        GLD_LDS16(Bt + (size_t)(n0 + srow0) * K + k0 + scol, &Bs[srow0 & ~15][0]);
        GLD_LDS16(Bt + (size_t)(n0 + srow1) * K + k0 + scol, &Bs[srow1 & ~15][0]);
        __syncthreads();
        bf16x8 af[4], bfr[4];
#pragma unroll
        for (int mb = 0; mb < 4; ++mb)
            af[mb] = *(const bf16x8*)&As[wm + (mb << 4) + l16][quad << 3];
#pragma unroll
        for (int nb = 0; nb < 4; ++nb)
            bfr[nb] = *(const bf16x8*)&Bs[wn + (nb << 4) + l16][quad << 3];
#pragma unroll
        for (int mb = 0; mb < 4; ++mb)
#pragma unroll
            for (int nb = 0; nb < 4; ++nb)
                acc[mb][nb] = MFMA16(af[mb], bfr[nb], acc[mb][nb]);
    }

    // Q pre-scaled by log2(e)/sqrt(128) for base-2 softmax
    const float qscale = 0.12751740806338946f;
#pragma unroll
    for (int nb = 0; nb < 4; ++nb) {
        int gn = n0 + wn + (nb << 4) + l16;
        float bv = bias[gn];
        int head = gn / 384, f = gn - head * 384;
#pragma unroll
        for (int mb = 0; mb < 4; ++mb) {
#pragma unroll
            for (int r = 0; r < 4; ++r) {
                int gm = m0 + wm + (mb << 4) + (quad << 2) + r;
                float v = acc[mb][nb][r] + bv;
                int b = gm >> 11, s = gm & 2047;
                int bhh = (b << 5) + head;
                if (f < 128) {
                    Qo[((size_t)bhh * 2048 + s) * 128 + f] = f2bf(v * qscale);
                } else if (f < 256) {
                    Ko[((size_t)bhh * 2048 + s) * 128 + (f - 128)] = f2bf(v);
                } else {
                    Vo[((size_t)bhh * 128 + (f - 256)) * 2048 + s] = f2bf(v);
                }
            }
        }
    }
}

// ---------------------------------------------------------------- out GEMM
__global__ __launch_bounds__(256) void out_gemm_kernel(const short* __restrict__ A,
                                                       const short* __restrict__ Bt,
                                                       const float* __restrict__ bias,
                                                       float* __restrict__ Co) {
    const int K = 4096, N = 4096;
    __shared__ short As[128][32];
    __shared__ short Bs[128][32];
    const int t = threadIdx.x;
    const int m0 = blockIdx.x << 7;
    const int n0 = blockIdx.y << 7;
    const int lane = t & 63;
    const int w = t >> 6;
    const int l16 = lane & 15;
    const int quad = lane >> 4;
    const int wm = (w >> 1) << 6;
    const int wn = (w & 1) << 6;

    const int srow0 = (w << 5) + (lane >> 2);
    const int srow1 = srow0 + 16;
    const int scol = (lane & 3) << 3;

    f32x4 acc[4][4];
#pragma unroll
    for (int i = 0; i < 4; ++i)
#pragma unroll
        for (int j = 0; j < 4; ++j) acc[i][j] = (f32x4){0.f, 0.f, 0.f, 0.f};

    for (int k0 = 0; k0 < K; k0 += 32) {
        __syncthreads();
        GLD_LDS16(A + (size_t)(m0 + srow0) * K + k0 + scol, &As[srow0 & ~15][0]);
        GLD_LDS16(A + (size_t)(m0 + srow1) * K + k0 + scol, &As[srow1 & ~15][0]);
        GLD_LDS16(Bt + (size_t)(n0 + srow0) * K + k0 + scol, &Bs[srow0 & ~15][0]);
        GLD_LDS16(Bt + (size_t)(n0 + srow1) * K + k0 + scol, &Bs[srow1 & ~15][0]);
        __syncthreads();
        bf16x8 af[4], bfr[4];
#pragma unroll
        for (int mb = 0; mb < 4; ++mb)
            af[mb] = *(const bf16x8*)&As[wm + (mb << 4) + l16][quad << 3];
#pragma unroll
        for (int nb = 0; nb < 4; ++nb)
            bfr[nb] = *(const bf16x8*)&Bs[wn + (nb << 4) + l16][quad << 3];
#pragma unroll
        for (int mb = 0; mb < 4; ++mb)
#pragma unroll
            for (int nb = 0; nb < 4; ++nb)
                acc[mb][nb] = MFMA16(af[mb], bfr[nb], acc[mb][nb]);
    }

#pragma unroll
    for (int nb = 0; nb < 4; ++nb) {
        int gn = n0 + wn + (nb << 4) + l16;
        float bv = bias[gn];
#pragma unroll
        for (int mb = 0; mb < 4; ++mb) {
#pragma unroll
            for (int r = 0; r < 4; ++r) {
                int gm = m0 + wm + (mb << 4) + (quad << 2) + r;
                Co[(size_t)gm * N + gn] = acc[mb][nb][r] + bv;
            }
        }
    }
}

// ---------------------------------------------------------------- flash attention
// grid (32, 64): qt = 31-bx (heavy first), bh = by. Base-2 online softmax,
// l via ones-column in V (MFMA computes row sums), diag-tile-only masking.
__global__ __launch_bounds__(256) void attn_kernel(const short* __restrict__ Q,
                                                   const short* __restrict__ Kt,
                                                   const short* __restrict__ Vt,
                                                   const float* __restrict__ cbias,
                                                   short* __restrict__ Ot) {
    __shared__ short Ks[64][132];    // [key][d]
    __shared__ short Vs[144][68];    // [d][key]; rows 128..143: ones-column block
    __shared__ short Ps[4][16][68];  // per-wave P tile [q][key]
    const int t = threadIdx.x;
    const int w = t >> 6;
    const int lane = t & 63;
    const int l16 = lane & 15;
    const int quad = lane >> 4;
    const int qt = 31 - blockIdx.x;
    const int bh = blockIdx.y;
    const int b = bh >> 5;
    const int h = bh & 31;
    const int q0t = qt << 6;

    const short* Qp = Q + (size_t)bh * 2048 * 128;
    const short* Kp = Kt + (size_t)bh * 2048 * 128;
    const short* Vp = Vt + (size_t)bh * 128 * 2048;
    const float* cb = cbias + (size_t)bh * 2048;

    const int kr = t >> 4, kc = (t & 15) << 3;
    const int vr = t >> 3, vc = (t & 7) << 3;

    // ones-column block: Vs row 128 = 1.0 (keys 0..63), rows 129..143 = 0. Written once.
    for (int idx = t; idx < 16 * 68; idx += 256) {
        int rr = idx / 68, cc = idx - rr * 68;
        Vs[128 + rr][cc] = (rr == 0 && cc < 64) ? (short)0x3F80 : (short)0;
    }

    bf16x8 aq[4];
    const int myq = q0t + (w << 4) + l16;
#pragma unroll
    for (int kd = 0; kd < 4; ++kd)
        aq[kd] = *(const bf16x8*)(Qp + (size_t)myq * 128 + (kd << 5) + (quad << 3));

    f32x4 acc[9];   // [0..7]: O columns; [8]: l in column 0
#pragma unroll
    for (int c = 0; c < 9; ++c) acc[c] = (f32x4){0.f, 0.f, 0.f, 0.f};
    float mrow[4];
#pragma unroll
    for (int r = 0; r < 4; ++r) mrow[r] = -3.0e38f;

    const int ktiles = qt + 1;

    bf16x8 Kreg[4], Vreg[4];
#pragma unroll
    for (int i = 0; i < 4; ++i) {
        Kreg[i] = *(const bf16x8*)(Kp + (size_t)(kr + (i << 4)) * 128 + kc);
        Vreg[i] = *(const bf16x8*)(Vp + (size_t)(vr + (i << 5)) * 2048 + vc);
    }

    for (int kt = 0; kt < ktiles; ++kt) {
        const int kk = kt << 6;
        __syncthreads();
#pragma unroll
        for (int i = 0; i < 4; ++i) {
            *(bf16x8*)&Ks[kr + (i << 4)][kc] = Kreg[i];
            *(bf16x8*)&Vs[vr + (i << 5)][vc] = Vreg[i];
        }
        if (kt + 1 < ktiles) {
            const int nk = kk + 64;
#pragma unroll
            for (int i = 0; i < 4; ++i) {
                Kreg[i] = *(const bf16x8*)(Kp + (size_t)(nk + kr + (i << 4)) * 128 + kc);
                Vreg[i] = *(const bf16x8*)(Vp + (size_t)(vr + (i << 5)) * 2048 + nk + vc);
            }
        }
        __syncthreads();

        float biasv[4];
#pragma unroll
        for (int j = 0; j < 4; ++j)
            biasv[j] = cb[kk + (j << 4) + l16];

        f32x4 sf[4];
#pragma unroll
        for (int nb = 0; nb < 4; ++nb) {
            sf[nb] = (f32x4){0.f, 0.f, 0.f, 0.f};
#pragma unroll
            for (int kd = 0; kd < 4; ++kd) {
                bf16x8 bk = *(const bf16x8*)&Ks[(nb << 4) + l16][(kd << 5) + (quad << 3)];
                sf[nb] = MFMA16(aq[kd], bk, sf[nb]);
            }
        }

        const int qrb = q0t + (w << 4) + (quad << 2);
        const bool diag = (kt == ktiles - 1);   // only the last tile straddles causality
        float alpha[4];
#pragma unroll
        for (int r = 0; r < 4; ++r) {
            float s[4];
#pragma unroll
            for (int j = 0; j < 4; ++j) s[j] = sf[j][r] + biasv[j];
            if (diag) {
                int qr = qrb + r;
#pragma unroll
                for (int j = 0; j < 4; ++j)
                    if (kk + (j << 4) + l16 > qr) s[j] = -3.0e38f;
            }
            float mx = fmaxf(fmaxf(s[0], s[1]), fmaxf(s[2], s[3]));
            mx = fmaxf(mx, __shfl_xor(mx, 1));
            mx = fmaxf(mx, __shfl_xor(mx, 2));
            mx = fmaxf(mx, __shfl_xor(mx, 4));
            mx = fmaxf(mx, __shfl_xor(mx, 8));
            float mnew = fmaxf(mrow[r], mx);
            alpha[r] = fexp2(mrow[r] - mnew);
            mrow[r] = mnew;
            int pq = (quad << 2) + r;
#pragma unroll
            for (int j = 0; j < 4; ++j)
                Ps[w][pq][(j << 4) + l16] = f2bf_trunc(fexp2(s[j] - mnew));
        }

        // PV (+ l in frag 8 via ones-column); same-wave LDS write->read, no barrier
        bf16x8 ap0 = *(const bf16x8*)&Ps[w][l16][quad << 3];
        bf16x8 ap1 = *(const bf16x8*)&Ps[w][l16][32 + (quad << 3)];
#pragma unroll
        for (int c = 0; c < 9; ++c) {
            bf16x8 bv0 = *(const bf16x8*)&Vs[(c << 4) + l16][quad << 3];
            bf16x8 bv1 = *(const bf16x8*)&Vs[(c << 4) + l16][32 + (quad << 3)];
            f32x4 ac = acc[c];
            ac[0] *= alpha[0]; ac[1] *= alpha[1]; ac[2] *= alpha[2]; ac[3] *= alpha[3];
            ac = MFMA16(ap0, bv0, ac);
            acc[c] = MFMA16(ap1, bv1, ac);
        }
    }

    // l lives in acc[8] column 0 (lanes with l16==0); broadcast within row group
    float inv[4];
#pragma unroll
    for (int r = 0; r < 4; ++r) {
        float l = __shfl(acc[8][r], quad << 4);
        inv[r] = (l > 0.f) ? 1.0f / l : 0.f;
    }
    const int qbase = q0t + (w << 4) + (quad << 2);
#pragma unroll
    for (int c = 0; c < 8; ++c) {
        int d = (c << 4) + l16;
#pragma unroll
        for (int r = 0; r < 4; ++r) {
            int q = qbase + r;
            Ot[(size_t)(b * 2048 + q) * 4096 + h * 128 + d] = f2bf(acc[c][r] * inv[r]);
        }
    }
}

// ---------------------------------------------------------------- launch
extern "C" void kernel_launch(void* const* d_in, const int* in_sizes, int n_in,
                              void* d_out, int out_size, void* d_ws, size_t ws_size,
                              hipStream_t stream) {
    const float* hidden = (const float*)d_in[0];
    const float* alibi  = (const float*)d_in[1];
    const float* w_qkv  = (const float*)d_in[2];
    const float* b_qkv  = (const float*)d_in[3];
    const float* w_out  = (const float*)d_in[4];
    const float* b_out  = (const float*)d_in[5];
    const int*   amask  = (const int*)d_in[6];
    float* out = (float*)d_out;

    char* ws = (char*)d_ws;
    short* hid_bf = (short*)(ws);                       // 32 MB
    short* wqkv_t = (short*)(ws + 33554432ull);         // 96 MB
    short* wout_t = wqkv_t;                             // 32 MB, reuses wqkv_t region
    float* cbias  = (float*)(ws + 67108864ull);         // 512 KB, after wout_t, inside old wqkv_t region
    short* Qb     = (short*)(ws + 134217728ull);
    short* Kb     = (short*)(ws + 167772160ull);
    short* Vb     = (short*)(ws + 201326592ull);
    short* attn_o = hid_bf;

    cvt_kernel<<<16384, 256, 0, stream>>>(hidden, hid_bf, 4194304);
    transpose_cvt_kernel<<<dim3(384, 128), 256, 0, stream>>>(w_qkv, wqkv_t, 4096, 12288);
    qkv_gemm_kernel<<<dim3(32, 96), 256, 0, stream>>>(hid_bf, wqkv_t, b_qkv, Qb, Kb, Vb);
    // cbias overlaps old wqkv_t storage -> must run after qkv_gemm consumed it
    bias_prep_kernel<<<512, 256, 0, stream>>>(alibi, amask, cbias);
    transpose_cvt_kernel<<<dim3(128, 128), 256, 0, stream>>>(w_out, wout_t, 4096, 4096);
    attn_kernel<<<dim3(32, 64), 256, 0, stream>>>(Qb, Kb, Vb, cbias, attn_o);
    out_gemm_kernel<<<dim3(32, 32), 256, 0, stream>>>(attn_o, wout_t, b_out, out);
}